// Round 1
// baseline (691.015 us; speedup 1.0000x reference)
//
#include <hip/hip_runtime.h>
#include <math.h>

// ---------------------------------------------------------------------------
// MPConv round 3: bf16 MFMA for both GEMMs + precomputed bf16 x.
//  - prep kernels: W1[160,64],W2[64,64] f32 -> bf16 transposed [n][k] in d_ws
//                  x [N,64] f32 -> bf16 [N][64] in d_ws (if ws_size allows)
//  - main kernel: block = 4 waves, 256 edges. Per wave: 64 edges.
//      GEMM1: 4 Mtile x 4 Ntile x 5 Kstep mfma_f32_16x16x32_bf16
//             A-frags for k<128 load bf16 x directly (no f32 gather+pack)
//      LN+GELU: shfl_xor reduce within 16-lane C-layout groups
//      H -> LDS (stride 72 bf16) -> A-frags for GEMM2 (2 Ksteps)
//      scatter: unsafeAtomicAdd per (edge, channel)
// ---------------------------------------------------------------------------

using short8 = __attribute__((ext_vector_type(8))) short;
using f32x4  = __attribute__((ext_vector_type(4))) float;

#define LDH 72   // LDS stride for H tile, in bf16 elements (64+8 pad)

static __device__ __forceinline__ short f2bf(float f) {
    unsigned u = __float_as_uint(f);
    u += 0x7FFFu + ((u >> 16) & 1u);        // round-to-nearest-even
    return (short)(u >> 16);
}

static __device__ __forceinline__ short8 pack8(float4 a, float4 b) {
    short8 r;
    r[0] = f2bf(a.x); r[1] = f2bf(a.y); r[2] = f2bf(a.z); r[3] = f2bf(a.w);
    r[4] = f2bf(b.x); r[5] = f2bf(b.y); r[6] = f2bf(b.z); r[7] = f2bf(b.w);
    return r;
}

// ---- weight prep: f32 [k][n] -> bf16 [n][k] ------------------------------
__global__ void prep_weights(const float* __restrict__ W1,
                             const float* __restrict__ W2,
                             short* __restrict__ Wt1,   // [64][160]
                             short* __restrict__ Wt2)   // [64][64]
{
    int t = blockIdx.x * blockDim.x + threadIdx.x;
    if (t < 160 * 64) {
        int k = t / 64, n = t % 64;
        Wt1[n * 160 + k] = f2bf(W1[t]);
    }
    int t2 = t - 160 * 64;
    if (t2 >= 0 && t2 < 64 * 64) {
        int k = t2 / 64, n = t2 % 64;
        Wt2[n * 64 + k] = f2bf(W2[t2]);
    }
}

// ---- x prep: f32 [N,64] -> bf16 [N][64] (8 elems / thread) ---------------
__global__ void prep_x_bf16(const float* __restrict__ x,
                            short* __restrict__ xbf,
                            int total8)
{
    int t = blockIdx.x * blockDim.x + threadIdx.x;
    if (t < total8) {
        const float4* xf4 = (const float4*)x;
        float4 a = xf4[2 * t];
        float4 b = xf4[2 * t + 1];
        ((short8*)xbf)[t] = pack8(a, b);
    }
}

template <bool XBF>
__global__ __launch_bounds__(256) void mpconv_mfma(
    const float* __restrict__ x,      // [N,64]
    const short* __restrict__ xbf,    // [N][64] bf16 (valid iff XBF)
    const int*   __restrict__ ei,     // [2,E]
    const float* __restrict__ ea,     // [E,32]
    const short* __restrict__ Wt1,    // [64][160] bf16
    const float* __restrict__ b1,
    const float* __restrict__ gam,
    const float* __restrict__ bet,
    const short* __restrict__ Wt2,    // [64][64] bf16
    const float* __restrict__ b2,
    float*       __restrict__ out,    // [N,64]
    int E)
{
    __shared__ __align__(16) short Hlds[4][64][LDH];   // 36,864 B

    const int wave = threadIdx.x >> 6;
    const int lane = threadIdx.x & 63;
    const int g    = lane >> 4;        // quad id 0..3
    const int col  = lane & 15;
    const int eb   = blockIdx.x * 256 + wave * 64;     // wave's edge base

    // edges whose A-rows this lane loads (row m = col in each 16-row M tile)
    int aedge[4], ii[4], jj[4];
#pragma unroll
    for (int mt = 0; mt < 4; mt++) {
        int e = eb + mt * 16 + col;
        e = (e < E) ? e : (E - 1);     // clamp; invalid rows skipped at scatter
        aedge[mt] = e;
        ii[mt] = ei[e];
        jj[mt] = ei[E + e];
    }

    // per-lane channel params for its 4 columns (col + 16*nt)
    float b1c[4], gc[4], bc[4], b2c[4];
#pragma unroll
    for (int nt = 0; nt < 4; nt++) {
        int c = col + 16 * nt;
        b1c[nt] = b1[c]; gc[nt] = gam[c]; bc[nt] = bet[c]; b2c[nt] = b2[c];
    }

    // ---- GEMM1: [64,160] @ [160,64] -----------------------------------
    f32x4 acc[4][4];
#pragma unroll
    for (int mt = 0; mt < 4; mt++)
#pragma unroll
        for (int nt = 0; nt < 4; nt++)
            acc[mt][nt] = (f32x4){0.f, 0.f, 0.f, 0.f};

#pragma unroll
    for (int ks = 0; ks < 5; ks++) {
        const int k0 = ks * 32;
        const int kk = k0 + g * 8;     // this quad's k-chunk (8 wide)

        short8 afrag[4];
#pragma unroll
        for (int mt = 0; mt < 4; mt++) {
            if (XBF && k0 < 64) {
                afrag[mt] = *(const short8*)(xbf + (size_t)ii[mt] * 64 + kk);
            } else if (XBF && k0 < 128) {
                afrag[mt] = *(const short8*)(xbf + (size_t)jj[mt] * 64 + (kk - 64));
            } else {
                const float* s;
                if (k0 < 64)       s = x  + (size_t)ii[mt] * 64 + kk;
                else if (k0 < 128) s = x  + (size_t)jj[mt] * 64 + (kk - 64);
                else               s = ea + (size_t)aedge[mt] * 32 + (kk - 128);
                float4 a = *(const float4*)s;
                float4 b = *(const float4*)(s + 4);
                afrag[mt] = pack8(a, b);
            }
        }
        short8 bfrag[4];
#pragma unroll
        for (int nt = 0; nt < 4; nt++)
            bfrag[nt] = *(const short8*)(Wt1 + (size_t)(col + 16 * nt) * 160 + kk);

#pragma unroll
        for (int mt = 0; mt < 4; mt++)
#pragma unroll
            for (int nt = 0; nt < 4; nt++)
                acc[mt][nt] = __builtin_amdgcn_mfma_f32_16x16x32_bf16(
                    afrag[mt], bfrag[nt], acc[mt][nt], 0, 0, 0);
    }

    // ---- +b1, LayerNorm, GELU, write H to LDS -------------------------
    // C layout: row = g*4 + r, col = col + 16*nt  (within each 16x16 tile)
#pragma unroll
    for (int mt = 0; mt < 4; mt++) {
        float s[4] = {0.f, 0.f, 0.f, 0.f};
        float q[4] = {0.f, 0.f, 0.f, 0.f};
#pragma unroll
        for (int nt = 0; nt < 4; nt++) {
#pragma unroll
            for (int r = 0; r < 4; r++) {
                float v = acc[mt][nt][r] + b1c[nt];
                acc[mt][nt][r] = v;
                s[r] += v;
                q[r] += v * v;
            }
        }
#pragma unroll
        for (int m = 1; m < 16; m <<= 1) {
#pragma unroll
            for (int r = 0; r < 4; r++) {
                s[r] += __shfl_xor(s[r], m);
                q[r] += __shfl_xor(q[r], m);
            }
        }
#pragma unroll
        for (int r = 0; r < 4; r++) {
            float mu  = s[r] * (1.0f / 64.0f);
            float var = q[r] * (1.0f / 64.0f) - mu * mu;
            float inv = rsqrtf(var + 1e-5f);
            int row = mt * 16 + g * 4 + r;
#pragma unroll
            for (int nt = 0; nt < 4; nt++) {
                float h = (acc[mt][nt][r] - mu) * inv * gc[nt] + bc[nt];
                h = 0.5f * h * (1.0f + erff(h * 0.70710678118654752f));
                Hlds[wave][row][col + 16 * nt] = f2bf(h);
            }
        }
    }
    __syncthreads();

    // ---- GEMM2: [64,64] @ [64,64] -------------------------------------
    f32x4 acc2[4][4];
#pragma unroll
    for (int mt = 0; mt < 4; mt++)
#pragma unroll
        for (int nt = 0; nt < 4; nt++)
            acc2[mt][nt] = (f32x4){0.f, 0.f, 0.f, 0.f};

#pragma unroll
    for (int ks = 0; ks < 2; ks++) {
        const int kk = ks * 32 + g * 8;
        short8 af[4], bf[4];
#pragma unroll
        for (int mt = 0; mt < 4; mt++)
            af[mt] = *(const short8*)&Hlds[wave][mt * 16 + col][kk];
#pragma unroll
        for (int nt = 0; nt < 4; nt++)
            bf[nt] = *(const short8*)(Wt2 + (size_t)(col + 16 * nt) * 64 + kk);
#pragma unroll
        for (int mt = 0; mt < 4; mt++)
#pragma unroll
            for (int nt = 0; nt < 4; nt++)
                acc2[mt][nt] = __builtin_amdgcn_mfma_f32_16x16x32_bf16(
                    af[mt], bf[nt], acc2[mt][nt], 0, 0, 0);
    }

    // ---- +b2 and scatter-add to out[j] --------------------------------
#pragma unroll
    for (int mt = 0; mt < 4; mt++) {
#pragma unroll
        for (int r = 0; r < 4; r++) {
            int e = eb + mt * 16 + g * 4 + r;
            if (e < E) {
                int dst = ei[E + e];           // wave-uniform per 16-lane group
                float* op = out + (size_t)dst * 64 + col;
#pragma unroll
                for (int nt = 0; nt < 4; nt++)
                    unsafeAtomicAdd(op + 16 * nt, acc2[mt][nt][r] + b2c[nt]);
            }
        }
    }
}

extern "C" void kernel_launch(void* const* d_in, const int* in_sizes, int n_in,
                              void* d_out, int out_size, void* d_ws, size_t ws_size,
                              hipStream_t stream)
{
    const float* x   = (const float*)d_in[0];
    const int*   ei  = (const int*)  d_in[1];
    const float* ea  = (const float*)d_in[2];
    const float* W1  = (const float*)d_in[3];
    const float* b1  = (const float*)d_in[4];
    const float* gam = (const float*)d_in[5];
    const float* bet = (const float*)d_in[6];
    const float* W2  = (const float*)d_in[7];
    const float* b2  = (const float*)d_in[8];
    float* out = (float*)d_out;

    const int E = in_sizes[1] / 2;
    const int N = in_sizes[0] / 64;

    // workspace layout: Wt1 bf16 [64][160] | Wt2 bf16 [64][64] | xbf bf16 [N][64]
    short* Wt1 = (short*)d_ws;
    short* Wt2 = Wt1 + 160 * 64;
    const size_t wbytes = (size_t)(160 * 64 + 64 * 64) * sizeof(short);  // 28,672
    short* xbf = (short*)((char*)d_ws + wbytes);
    const size_t need = wbytes + (size_t)N * 64 * sizeof(short);
    const bool use_xbf = (ws_size >= need);

    hipMemsetAsync(d_out, 0, (size_t)out_size * sizeof(float), stream);

    {
        int total = 160 * 64 + 64 * 64;
        int grid = (total + 255) / 256;
        hipLaunchKernelGGL(prep_weights, dim3(grid), dim3(256), 0, stream,
                           W1, W2, Wt1, Wt2);
    }
    if (use_xbf) {
        int total8 = N * 8;                       // N*64 elems / 8 per thread
        int grid = (total8 + 255) / 256;
        hipLaunchKernelGGL(prep_x_bf16, dim3(grid), dim3(256), 0, stream,
                           x, xbf, total8);
    }
    {
        int grid = (E + 255) / 256;
        if (use_xbf)
            hipLaunchKernelGGL(mpconv_mfma<true>, dim3(grid), dim3(256), 0, stream,
                               x, xbf, ei, ea, Wt1, b1, gam, bet, Wt2, b2, out, E);
        else
            hipLaunchKernelGGL(mpconv_mfma<false>, dim3(grid), dim3(256), 0, stream,
                               x, xbf, ei, ea, Wt1, b1, gam, bet, Wt2, b2, out, E);
    }
}